// Round 1
// 1064.588 us; speedup vs baseline: 1.3034x; 1.3034x over previous
//
#include <hip/hip_runtime.h>
#include <stdint.h>

typedef __bf16 bf16;
typedef __bf16 bf16x4 __attribute__((ext_vector_type(4)));
typedef __bf16 bf16x8 __attribute__((ext_vector_type(8)));
typedef float f32x4 __attribute__((ext_vector_type(4)));

#define GLD_LDS16(g, l)                                                        \
  __builtin_amdgcn_global_load_lds(                                            \
      (const __attribute__((address_space(1))) void*)(g),                      \
      (__attribute__((address_space(3))) void*)(l), 16, 0, 0)

#define BAR() asm volatile("s_barrier" ::: "memory")
#define LGKM0() asm volatile("s_waitcnt lgkmcnt(0)" ::: "memory")
#define VMW(n) asm volatile("s_waitcnt vmcnt(" #n ")" ::: "memory")
#define PRIO(x) __builtin_amdgcn_s_setprio(x)

// ---------------------------------------------------------------- init: zero ssq accumulators
__global__ void k_init(float* s) {
  if (threadIdx.x < 3) s[threadIdx.x] = 0.0f;
}

// ---------------------------------------------------------------- cast x fp32 -> bf16, fused ||x||^2
__global__ void k_cast_ssq(const float* __restrict__ x, bf16* __restrict__ xb,
                           float* __restrict__ ssq, int n4) {
  int tid = blockIdx.x * blockDim.x + threadIdx.x;
  int stride = gridDim.x * blockDim.x;
  const float4* x4 = (const float4*)x;
  bf16x4* xb4 = (bf16x4*)xb;
  float acc = 0.f;
  for (int i = tid; i < n4; i += stride) {
    float4 v = x4[i];
    acc += v.x * v.x + v.y * v.y + v.z * v.z + v.w * v.w;
    bf16x4 b;
    b.x = (bf16)v.x; b.y = (bf16)v.y; b.z = (bf16)v.z; b.w = (bf16)v.w;
    xb4[i] = b;
  }
#pragma unroll
  for (int off = 32; off; off >>= 1) acc += __shfl_down(acc, off);
  __shared__ float red[4];
  if ((threadIdx.x & 63) == 0) red[threadIdx.x >> 6] = acc;
  __syncthreads();
  if (threadIdx.x == 0) atomicAdd(ssq, red[0] + red[1] + red[2] + red[3]);
}

// ---------------------------------------------------------------- build Wt (bf16, [out=4096][in=4096] row-major)
__global__ void k_buildW(const float* __restrict__ c0, const float* __restrict__ c1,
                         const float* __restrict__ c2, bf16* __restrict__ Wt) {
  int t = blockIdx.x * 256 + threadIdx.x;  // 4096 * 16 * 16 threads
  int j = t >> 8;
  int i0 = (t >> 4) & 15;
  int i1 = t & 15;
  int j0 = j >> 8, j1 = (j >> 4) & 15, j2 = j & 15;
  float t0[8];
#pragma unroll
  for (int r1 = 0; r1 < 8; ++r1) t0[r1] = c0[(i0 * 16 + j0) * 8 + r1];
  float a[8];
#pragma unroll
  for (int r2 = 0; r2 < 8; ++r2) {
    float s = 0.f;
#pragma unroll
    for (int r1 = 0; r1 < 8; ++r1) s += t0[r1] * c1[((r1 * 16 + i1) * 16 + j1) * 8 + r2];
    a[r2] = s;
  }
  union { bf16 h[16]; bf16x8 v[2]; } u;
#pragma unroll
  for (int i2 = 0; i2 < 16; ++i2) {
    float s = 0.f;
#pragma unroll
    for (int r2 = 0; r2 < 8; ++r2) s += a[r2] * c2[(r2 * 16 + i2) * 16 + j2];
    u.h[i2] = (bf16)s;
  }
  bf16* dst = Wt + (size_t)j * 4096 + i0 * 256 + i1 * 16;
  ((bf16x8*)dst)[0] = u.v[0];
  ((bf16x8*)dst)[1] = u.v[1];
}

// ---------------------------------------------------------------- 256x256 8-phase BT-form GEMM
// C[m,n] = sum_k A[m,k] * Bt[n,k].  BM=BN=256, BK=64, 512 thr = 8 waves (2M x 4N).
// Wave (wm,wn) owns interleaved sub-tiles: rows {wm*64..+63} u {128+wm*64..+63},
// cols {wn*32..+31} u {128+wn*32..+31}  -> stage units A0/A1/B0/B1 (128 rows x 64 cols,
// 16 KB each) are each consumed by ds_reads in exactly ONE phase of a K-tile.
// LDS: 2 x 64KB double buffer.  8 phases/iter (2 K-tiles); each phase:
//   {ds_read subtile | issue 1 stage unit (2x global_load_lds) -> BAR -> lgkmcnt(0)
//    -> setprio(1) 16xMFMA setprio(0) -> BAR}
// Counted vmcnt(6) ONLY at phases 4/8 (3 units = 6 loads stay in flight, never drain).
// LDS chunk swizzle: slot (row, c) holds global chunk c ^ (row&7) (pre-swizzled global
// source for global_load_lds; same xor on ds_read) -> bank-optimal ds_read_b128.
// MODE 0: xl0 = acc + bias + gate0 ; bf_out ; ssq_out
// MODE 1: G (symmetric): blocks bx<by exit; write acc and mirror
// MODE 2: xl1 = 2*xl0 - acc + (gate1-gate0) ; bf_out ; ssq_out          [A = xl0]
// MODE 3: out = xl_prev - acc + xl0 + (gate2-gate0)  (fp32)             [A = xl1]
template <int MODE>
__global__ __launch_bounds__(512, 2) void k_gemm(
    const bf16* __restrict__ A, const bf16* __restrict__ Bt, int M, int N, int K,
    const float* __restrict__ bias, const bf16* __restrict__ xl0,
    const bf16* __restrict__ xl_prev, float* f32_out, bf16* __restrict__ bf_out,
    const float* __restrict__ ssq_a, const float* __restrict__ ssq_b,
    float* __restrict__ ssq_out) {
  // XCD-aware bijective swizzle (all grids have nb % 8 == 0)
  const int nb = gridDim.x * gridDim.y;
  const int lin = blockIdx.y * gridDim.x + blockIdx.x;
  const int sw = (lin & 7) * (nb >> 3) + (lin >> 3);
  const int bx = sw % gridDim.x, by = sw / gridDim.x;
  if constexpr (MODE == 1) {
    if (bx < by) return;  // G symmetric: upper triangle only
  }

  __shared__ char smem[131072];  // 2 x (A0|A1|B0|B1), 16KB units

  const int t = threadIdx.x;
  const int w = t >> 6, lane = t & 63;
  const int q = lane >> 4, lr = lane & 15;
  const int wm = w & 1, wn = w >> 1;

  // gate: hoisted above the pipeline; VMW(0) drains it so manual vmcnt counts stay exact
  float gate = 0.f;
  if constexpr (MODE == 0) {
    gate = (*ssq_a > 1.0f) ? 0.f : -1.f;
  } else if constexpr (MODE == 2 || MODE == 3) {
    float g0 = (*ssq_a > 1.0f) ? 0.f : -1.f;
    float gt = (*ssq_b > 1.0f) ? 0.f : -1.f;
    gate = gt - g0;
  }
  VMW(0);

  // staging: thread t = LDS chunk t (row r0=t>>3, slot t&7) and chunk 512+t (row 64+r0).
  // slot (r,c) holds global chunk c ^ (r&7)  -> pre-swizzled global source column.
  const int r0 = t >> 3;
  const int ksrc = (t & 7) ^ (r0 & 7);
  const bf16* srcA = A + (size_t)(by * 256 + r0) * K + ksrc * 8;
  const bf16* srcB = Bt + (size_t)(bx * 256 + r0) * K + ksrc * 8;
  const int wofs = w << 10;

#define STAGE_A(h, kt, b)                                                              \
  do {                                                                                 \
    GLD_LDS16(srcA + (size_t)((h) * 128) * K + (kt) * 64,                              \
              smem + (b) * 65536 + (h) * 16384 + wofs);                                \
    GLD_LDS16(srcA + (size_t)((h) * 128 + 64) * K + (kt) * 64,                         \
              smem + (b) * 65536 + (h) * 16384 + 8192 + wofs);                         \
  } while (0)
#define STAGE_B(h, kt, b)                                                              \
  do {                                                                                 \
    GLD_LDS16(srcB + (size_t)((h) * 128) * K + (kt) * 64,                              \
              smem + (b) * 65536 + 32768 + (h) * 16384 + wofs);                        \
    GLD_LDS16(srcB + (size_t)((h) * 128 + 64) * K + (kt) * 64,                         \
              smem + (b) * 65536 + 32768 + (h) * 16384 + 8192 + wofs);                 \
  } while (0)

  // fragment-read lane constants (chunk = ks*4+q, xor row&7 = lr&7)
  const int aRow = (wm * 64 + lr) * 128;
  const int bRow = (wn * 32 + lr) * 128;
  const int cb0 = ((q ^ (lr & 7)) << 4);
  const int cb1 = (((4 + q) ^ (lr & 7)) << 4);

  f32x4 acc[8][4];
#pragma unroll
  for (int i = 0; i < 8; ++i)
#pragma unroll
    for (int j = 0; j < 4; ++j) acc[i][j] = (f32x4){0.f, 0.f, 0.f, 0.f};

  bf16x8 af[4][2];      // current m-sub A frags
  bf16x8 bfr[2][2][2];  // both n-sub B frags [ns][ni][ks]

#define LDA(ms, b)                                                                     \
  do {                                                                                 \
    const char* s_ = smem + (b) * 65536 + (ms) * 16384 + aRow;                         \
    _Pragma("unroll") for (int mi_ = 0; mi_ < 4; ++mi_) {                              \
      af[mi_][0] = *(const bf16x8*)(s_ + mi_ * 2048 + cb0);                            \
      af[mi_][1] = *(const bf16x8*)(s_ + mi_ * 2048 + cb1);                            \
    }                                                                                  \
  } while (0)
#define LDB(ns, b)                                                                     \
  do {                                                                                 \
    const char* s_ = smem + (b) * 65536 + 32768 + (ns) * 16384 + bRow;                 \
    _Pragma("unroll") for (int ni_ = 0; ni_ < 2; ++ni_) {                              \
      bfr[ns][ni_][0] = *(const bf16x8*)(s_ + ni_ * 2048 + cb0);                       \
      bfr[ns][ni_][1] = *(const bf16x8*)(s_ + ni_ * 2048 + cb1);                       \
    }                                                                                  \
  } while (0)
#define MFMA_Q(ms, ns)                                                                 \
  do {                                                                                 \
    PRIO(1);                                                                           \
    _Pragma("unroll") for (int mi_ = 0; mi_ < 4; ++mi_)                                \
    _Pragma("unroll") for (int ni_ = 0; ni_ < 2; ++ni_)                                \
    _Pragma("unroll") for (int ks_ = 0; ks_ < 2; ++ks_)                                \
        acc[(ms) * 4 + mi_][(ns) * 2 + ni_] =                                          \
            __builtin_amdgcn_mfma_f32_16x16x32_bf16(                                   \
                af[mi_][ks_], bfr[ns][ni_][ks_],                                       \
                acc[(ms) * 4 + mi_][(ns) * 2 + ni_], 0, 0, 0);                         \
    PRIO(0);                                                                           \
  } while (0)

  // prologue: tile0 (A0,B0,B1,A1) + tile1 (A0,B0,B1); vmcnt(6) -> tile0 landed,
  // newest 3 units (tile1 A0,B0,B1) stay in flight.
  STAGE_A(0, 0, 0); STAGE_B(0, 0, 0); STAGE_B(1, 0, 0); STAGE_A(1, 0, 0);
  STAGE_A(0, 1, 1); STAGE_B(0, 1, 1); STAGE_B(1, 1, 1);
  VMW(6);
  BAR();

  const int NT = K >> 6;  // 64 K-tiles
#pragma unroll 1
  for (int tt = 0; tt < (NT >> 1) - 1; ++tt) {
    const int T = tt << 1;
    // ---- tile T (buf0) ----
    // P1: Q(m0,n0); stage A1(T+1)->buf1 (buf1.A1 last read 2 phases ago)
    LDA(0, 0); LDB(0, 0);
    STAGE_A(1, T + 1, 1);
    BAR(); LGKM0();
    MFMA_Q(0, 0);
    BAR();
    // P2: Q(m0,n1); stage A0(T+2)->buf0 (buf0.A0 freed after P1)
    LDB(1, 0);
    STAGE_A(0, T + 2, 0);
    BAR(); LGKM0();
    MFMA_Q(0, 1);
    BAR();
    // P3: Q(m1,n1); stage B0(T+2) (buf0.B0 freed after P1)
    LDA(1, 0);
    STAGE_B(0, T + 2, 0);
    BAR(); LGKM0();
    MFMA_Q(1, 1);
    BAR();
    // P4: Q(m1,n0) from regs; stage B1(T+2) (freed after P2); publish tile T+1
    STAGE_B(1, T + 2, 0);
    VMW(6);
    BAR();
    MFMA_Q(1, 0);
    BAR();
    // ---- tile T+1 (buf1) ----
    // P5: stage A1(T+2)->buf0 (buf0.A1 freed after P3)
    LDA(0, 1); LDB(0, 1);
    STAGE_A(1, T + 2, 0);
    BAR(); LGKM0();
    MFMA_Q(0, 0);
    BAR();
    // P6
    LDB(1, 1);
    STAGE_A(0, T + 3, 1);
    BAR(); LGKM0();
    MFMA_Q(0, 1);
    BAR();
    // P7
    LDA(1, 1);
    STAGE_B(0, T + 3, 1);
    BAR(); LGKM0();
    MFMA_Q(1, 1);
    BAR();
    // P8: publish tile T+2
    STAGE_B(1, T + 3, 1);
    VMW(6);
    BAR();
    MFMA_Q(1, 0);
    BAR();
  }

  // epilogue pair: tiles NT-2 (buf0), NT-1 (buf1); only A1(NT-1) left to stage
  LDA(0, 0); LDB(0, 0);
  STAGE_A(1, NT - 1, 1);
  BAR(); LGKM0(); MFMA_Q(0, 0); BAR();
  LDB(1, 0);
  BAR(); LGKM0(); MFMA_Q(0, 1); BAR();
  LDA(1, 0);
  BAR(); LGKM0(); MFMA_Q(1, 1); BAR();
  VMW(0);  // drain: tile NT-1 fully landed
  BAR();
  MFMA_Q(1, 0);
  BAR();
  LDA(0, 1); LDB(0, 1);
  BAR(); LGKM0(); MFMA_Q(0, 0); BAR();
  LDB(1, 1);
  BAR(); LGKM0(); MFMA_Q(0, 1); BAR();
  LDA(1, 1);
  BAR(); LGKM0(); MFMA_Q(1, 1); BAR();
  MFMA_Q(1, 0);

  // C-write. C/D layout: col = lane&15, row = (lane>>4)*4 + reg  [m89-verified]
  float ssql = 0.f;
#pragma unroll
  for (int mi = 0; mi < 8; ++mi) {
    const int grow = by * 256 + ((mi & 4) ? 128 : 0) + wm * 64 + (mi & 3) * 16 + q * 4;
#pragma unroll
    for (int r = 0; r < 4; ++r) {
      const size_t rowb = (size_t)(grow + r) * N;
#pragma unroll
      for (int ni = 0; ni < 4; ++ni) {
        const int gcol = bx * 256 + ((ni & 2) ? 128 : 0) + wn * 32 + (ni & 1) * 16 + lr;
        const size_t idx = rowb + gcol;
        float v = acc[mi][ni][r];
        if constexpr (MODE == 0) {
          float xl = v + bias[gcol] + gate;
          bf_out[idx] = (bf16)xl;
          ssql += xl * xl;
        } else if constexpr (MODE == 1) {
          bf_out[idx] = (bf16)v;
          if (bx != by) bf_out[(size_t)gcol * N + (grow + r)] = (bf16)v;
        } else if constexpr (MODE == 2) {
          float xl = 2.0f * (float)xl0[idx] - v + gate;
          bf_out[idx] = (bf16)xl;
          ssql += xl * xl;
        } else {
          f32_out[idx] = (float)xl_prev[idx] - v + (float)xl0[idx] + gate;
        }
      }
    }
  }
  if constexpr (MODE == 0 || MODE == 2) {
#pragma unroll
    for (int off = 32; off; off >>= 1) ssql += __shfl_down(ssql, off);
    __syncthreads();  // pipeline fully drained; reuse smem for reduction
    float* red = (float*)smem;
    if (lane == 0) red[w] = ssql;
    __syncthreads();
    if (t == 0) {
      float s = 0.f;
#pragma unroll
      for (int i = 0; i < 8; ++i) s += red[i];
      atomicAdd(ssq_out, s);
    }
  }
#undef STAGE_A
#undef STAGE_B
#undef LDA
#undef LDB
#undef MFMA_Q
}

// ----------------------------------------------------------------
extern "C" void kernel_launch(void* const* d_in, const int* in_sizes, int n_in,
                              void* d_out, int out_size, void* d_ws, size_t ws_size,
                              hipStream_t stream) {
  const float* x = (const float*)d_in[0];
  const float* c0 = (const float*)d_in[1];
  const float* c1 = (const float*)d_in[2];
  const float* c2 = (const float*)d_in[3];
  const float* bias = (const float*)d_in[4];
  float* out = (float*)d_out;

  const int B = 8192, F = 4096;
  char* ws = (char*)d_ws;
  float* scal = (float*)ws;                              // [0]=ssq_x [1]=ssq_xl0 [2]=ssq_xl1
  bf16* xbf = (bf16*)(ws + 256);                         // 64 MiB (x bf16; reused as xl1)
  bf16* Wt = (bf16*)(ws + 256 + (size_t)67108864);       // 32 MiB
  bf16* G = (bf16*)(ws + 256 + (size_t)100663296);       // 32 MiB
  bf16* xl0 = (bf16*)(ws + 256 + (size_t)134217728);     // 64 MiB
  bf16* xl1 = xbf;  // xbf dead after mv GEMM

  k_init<<<1, 64, 0, stream>>>(scal);
  k_cast_ssq<<<1024, 256, 0, stream>>>(x, xbf, &scal[0], B * F / 4);
  k_buildW<<<4096, 256, 0, stream>>>(c0, c1, c2, Wt);

  // G = W^T W = Wt @ Wt^T  (BT form: A=Wt, Bt=Wt), symmetric -> triangle + mirror
  k_gemm<1><<<dim3(F / 256, F / 256), 512, 0, stream>>>(
      Wt, Wt, F, F, F, nullptr, nullptr, nullptr, nullptr, G, nullptr, nullptr, nullptr);
  dim3 g1(F / 256, B / 256);
  // xl0 = x@W + bias + gate0
  k_gemm<0><<<g1, 512, 0, stream>>>(xbf, Wt, B, F, F, bias, nullptr, nullptr,
                                    nullptr, xl0, &scal[0], nullptr, &scal[1]);
  // xl1 = 2*xl0 - xl0@G + (gate1-gate0)
  k_gemm<2><<<g1, 512, 0, stream>>>(xl0, G, B, F, F, nullptr, xl0, nullptr,
                                    nullptr, xl1, &scal[0], &scal[1], &scal[2]);
  // out = xl1 - xl1@G + xl0 + (gate2-gate0)
  k_gemm<3><<<g1, 512, 0, stream>>>(xl1, G, B, F, F, nullptr, xl0, xl1,
                                    out, nullptr, &scal[0], &scal[2], nullptr);
}

// Round 2
// 1055.115 us; speedup vs baseline: 1.3151x; 1.0090x over previous
//
#include <hip/hip_runtime.h>
#include <stdint.h>

typedef __bf16 bf16;
typedef __bf16 bf16x4 __attribute__((ext_vector_type(4)));
typedef __bf16 bf16x8 __attribute__((ext_vector_type(8)));
typedef float f32x4 __attribute__((ext_vector_type(4)));

#define GLD_LDS16(g, l)                                                        \
  __builtin_amdgcn_global_load_lds(                                            \
      (const __attribute__((address_space(1))) void*)(g),                      \
      (__attribute__((address_space(3))) void*)(l), 16, 0, 0)

#define BAR() asm volatile("s_barrier" ::: "memory")
#define VMW(n) asm volatile("s_waitcnt vmcnt(" #n ")" ::: "memory")
#define PRIO(x) __builtin_amdgcn_s_setprio(x)

// ---------------------------------------------------------------- init: zero ssq accumulators
__global__ void k_init(float* s) {
  if (threadIdx.x < 3) s[threadIdx.x] = 0.0f;
}

// ---------------------------------------------------------------- cast x fp32 -> bf16, fused ||x||^2
__global__ void k_cast_ssq(const float* __restrict__ x, bf16* __restrict__ xb,
                           float* __restrict__ ssq, int n4) {
  int tid = blockIdx.x * blockDim.x + threadIdx.x;
  int stride = gridDim.x * blockDim.x;
  const float4* x4 = (const float4*)x;
  bf16x4* xb4 = (bf16x4*)xb;
  float acc = 0.f;
  for (int i = tid; i < n4; i += stride) {
    float4 v = x4[i];
    acc += v.x * v.x + v.y * v.y + v.z * v.z + v.w * v.w;
    bf16x4 b;
    b.x = (bf16)v.x; b.y = (bf16)v.y; b.z = (bf16)v.z; b.w = (bf16)v.w;
    xb4[i] = b;
  }
#pragma unroll
  for (int off = 32; off; off >>= 1) acc += __shfl_down(acc, off);
  __shared__ float red[4];
  if ((threadIdx.x & 63) == 0) red[threadIdx.x >> 6] = acc;
  __syncthreads();
  if (threadIdx.x == 0) atomicAdd(ssq, red[0] + red[1] + red[2] + red[3]);
}

// ---------------------------------------------------------------- build Wt (bf16, [out=4096][in=4096] row-major)
__global__ void k_buildW(const float* __restrict__ c0, const float* __restrict__ c1,
                         const float* __restrict__ c2, bf16* __restrict__ Wt) {
  int t = blockIdx.x * 256 + threadIdx.x;  // 4096 * 16 * 16 threads
  int j = t >> 8;
  int i0 = (t >> 4) & 15;
  int i1 = t & 15;
  int j0 = j >> 8, j1 = (j >> 4) & 15, j2 = j & 15;
  float t0[8];
#pragma unroll
  for (int r1 = 0; r1 < 8; ++r1) t0[r1] = c0[(i0 * 16 + j0) * 8 + r1];
  float a[8];
#pragma unroll
  for (int r2 = 0; r2 < 8; ++r2) {
    float s = 0.f;
#pragma unroll
    for (int r1 = 0; r1 < 8; ++r1) s += t0[r1] * c1[((r1 * 16 + i1) * 16 + j1) * 8 + r2];
    a[r2] = s;
  }
  union { bf16 h[16]; bf16x8 v[2]; } u;
#pragma unroll
  for (int i2 = 0; i2 < 16; ++i2) {
    float s = 0.f;
#pragma unroll
    for (int r2 = 0; r2 < 8; ++r2) s += a[r2] * c2[(r2 * 16 + i2) * 16 + j2];
    u.h[i2] = (bf16)s;
  }
  bf16* dst = Wt + (size_t)j * 4096 + i0 * 256 + i1 * 16;
  ((bf16x8*)dst)[0] = u.v[0];
  ((bf16x8*)dst)[1] = u.v[1];
}

// ---------------------------------------------------------------- 256x256 8-phase BT-form GEMM core
// C[m,n] = sum_k A[m,k] * Bt[n,k].  BM=BN=256, BK=64, 512 thr = 8 waves (2M x 4N).
// Stage units A0/A1/B0/B1 (128 rows x 64 cols, 16 KB each); 2x64KB LDS double buffer.
// 8 phases / 2 K-tiles, ONE barrier per phase:
//   {stage 1 unit ; ds_reads for this phase's quadrant ; MFMA (compiler-counted lgkm) ; BAR}
// vmcnt(6) publish only at P4/P8 (3 units = 6 loads stay in flight, never drained).
// Hazard ledger (re-verified): every stage target last ds_read >=1 barrier earlier;
// every ds_read covered by a prior vmcnt(6)+BAR publish.
// LDS chunk swizzle: slot (row,c) holds global chunk c ^ (row&7) (pre-swizzled source).
#define STAGE_A(h, kt, b)                                                              \
  do {                                                                                 \
    GLD_LDS16(srcA + (size_t)((h) * 128) * K + (kt) * 64,                              \
              smem + (b) * 65536 + (h) * 16384 + wofs);                                \
    GLD_LDS16(srcA + (size_t)((h) * 128 + 64) * K + (kt) * 64,                         \
              smem + (b) * 65536 + (h) * 16384 + 8192 + wofs);                         \
  } while (0)
#define STAGE_B(h, kt, b)                                                              \
  do {                                                                                 \
    GLD_LDS16(srcB + (size_t)((h) * 128) * K + (kt) * 64,                              \
              smem + (b) * 65536 + 32768 + (h) * 16384 + wofs);                        \
    GLD_LDS16(srcB + (size_t)((h) * 128 + 64) * K + (kt) * 64,                         \
              smem + (b) * 65536 + 32768 + (h) * 16384 + 8192 + wofs);                 \
  } while (0)
#define LDA(ms, b)                                                                     \
  do {                                                                                 \
    const char* s_ = smem + (b) * 65536 + (ms) * 16384 + aRow;                         \
    _Pragma("unroll") for (int mi_ = 0; mi_ < 4; ++mi_) {                              \
      af[mi_][0] = *(const bf16x8*)(s_ + mi_ * 2048 + cb0);                            \
      af[mi_][1] = *(const bf16x8*)(s_ + mi_ * 2048 + cb1);                            \
    }                                                                                  \
  } while (0)
#define LDB(ns, b)                                                                     \
  do {                                                                                 \
    const char* s_ = smem + (b) * 65536 + 32768 + (ns) * 16384 + bRow;                 \
    _Pragma("unroll") for (int ni_ = 0; ni_ < 2; ++ni_) {                              \
      bfr[ns][ni_][0] = *(const bf16x8*)(s_ + ni_ * 2048 + cb0);                       \
      bfr[ns][ni_][1] = *(const bf16x8*)(s_ + ni_ * 2048 + cb1);                       \
    }                                                                                  \
  } while (0)
#define MFMA_Q(ms, ns)                                                                 \
  do {                                                                                 \
    PRIO(1);                                                                           \
    _Pragma("unroll") for (int mi_ = 0; mi_ < 4; ++mi_)                                \
    _Pragma("unroll") for (int ni_ = 0; ni_ < 2; ++ni_)                                \
    _Pragma("unroll") for (int ks_ = 0; ks_ < 2; ++ks_)                                \
        acc[(ms) * 4 + mi_][(ns) * 2 + ni_] =                                          \
            __builtin_amdgcn_mfma_f32_16x16x32_bf16(                                   \
                af[mi_][ks_], bfr[ns][ni_][ks_],                                       \
                acc[(ms) * 4 + mi_][(ns) * 2 + ni_], 0, 0, 0);                         \
    PRIO(0);                                                                           \
  } while (0)

__device__ __forceinline__ void run_core(const bf16* __restrict__ Ag,
                                         const bf16* __restrict__ Bg, const int K,
                                         const int bx, const int by, char* smem,
                                         f32x4 (&acc)[8][4]) {
  const int t = threadIdx.x;
  const int w = t >> 6, lane = t & 63;
  const int q = lane >> 4, lr = lane & 15;
  const int wm = w & 1, wn = w >> 1;

  const int r0 = t >> 3;
  const int ksrc = (t & 7) ^ (r0 & 7);
  const bf16* srcA = Ag + (size_t)(by * 256 + r0) * K + ksrc * 8;
  const bf16* srcB = Bg + (size_t)(bx * 256 + r0) * K + ksrc * 8;
  const int wofs = w << 10;

  const int aRow = (wm * 64 + lr) * 128;
  const int bRow = (wn * 32 + lr) * 128;
  const int cb0 = ((q ^ (lr & 7)) << 4);
  const int cb1 = (((4 + q) ^ (lr & 7)) << 4);

#pragma unroll
  for (int i = 0; i < 8; ++i)
#pragma unroll
    for (int j = 0; j < 4; ++j) acc[i][j] = (f32x4){0.f, 0.f, 0.f, 0.f};

  bf16x8 af[4][2];      // current m-sub A frags
  bf16x8 bfr[2][2][2];  // both n-sub B frags [ns][ni][ks]

  // prologue: tile0 (buf0) all 4 units + tile1 (buf1) A0,B0,B1.
  // vmcnt(6): tile0's 8 loads landed; tile1's 3 units (6 loads) in flight.
  STAGE_A(0, 0, 0); STAGE_B(0, 0, 0); STAGE_B(1, 0, 0); STAGE_A(1, 0, 0);
  STAGE_A(0, 1, 1); STAGE_B(0, 1, 1); STAGE_B(1, 1, 1);
  VMW(6);
  BAR();

  const int NT = K >> 6;  // 64 K-tiles
#pragma unroll 1
  for (int tt = 0; tt < (NT >> 1) - 1; ++tt) {
    const int T = tt << 1;
    // ---- tile T (buf0), quadrants Q00,Q01,Q11,Q10 ----
    STAGE_A(1, T + 1, 1);          // buf1.A1: last read prev-iter P7 (2 bars back)
    LDB(0, 0); LDA(0, 0);
    MFMA_Q(0, 0);
    BAR();
    STAGE_A(0, T + 2, 0);          // buf0.A0: read P1 (1 bar back)
    LDB(1, 0);
    MFMA_Q(0, 1);
    BAR();
    STAGE_B(0, T + 2, 0);          // buf0.B0: read P1 (2 bars back)
    LDA(1, 0);
    MFMA_Q(1, 1);
    BAR();
    STAGE_B(1, T + 2, 0);          // buf0.B1: read P2 (2 bars back)
    MFMA_Q(1, 0);                  // regs only (af from P3, bfr0 from P1)
    VMW(6);                        // publish tile T+1: drains P1's A1 + older
    BAR();
    // ---- tile T+1 (buf1) ----
    STAGE_A(1, T + 2, 0);          // buf0.A1: read P3 (2 bars back)
    LDB(0, 1); LDA(0, 1);
    MFMA_Q(0, 0);
    BAR();
    STAGE_A(0, T + 3, 1);          // buf1.A0: read P5 (1 bar back)
    LDB(1, 1);
    MFMA_Q(0, 1);
    BAR();
    STAGE_B(0, T + 3, 1);          // buf1.B0: read P5 (2 bars back)
    LDA(1, 1);
    MFMA_Q(1, 1);
    BAR();
    STAGE_B(1, T + 3, 1);          // buf1.B1: read P6 (2 bars back)
    MFMA_Q(1, 0);
    VMW(6);                        // publish tile T+2: drains P5's A1 + P2-P4
    BAR();
  }

  // epilogue pair: tiles NT-2 (buf0), NT-1 (buf1); only A1(NT-1) left to stage
  STAGE_A(1, NT - 1, 1);
  LDB(0, 0); LDA(0, 0);
  MFMA_Q(0, 0); BAR();
  LDB(1, 0);
  MFMA_Q(0, 1); BAR();
  LDA(1, 0);
  MFMA_Q(1, 1); BAR();
  MFMA_Q(1, 0);
  VMW(0);                          // tile NT-1 fully landed
  BAR();
  LDB(0, 1); LDA(0, 1);
  MFMA_Q(0, 0); BAR();
  LDB(1, 1);
  MFMA_Q(0, 1); BAR();
  LDA(1, 1);
  MFMA_Q(1, 1); BAR();
  MFMA_Q(1, 0);
}

// ---------------------------------------------------------------- fused G + MODE0 kernel
// grid = 768 1-D blocks (768%8==0 -> simple XCD swizzle bijective).
// swz<256: G = Wt@Wt^T (16x16 triangle, bx<by exit); swz>=256: xl0 = x@W + bias + gate0.
__global__ __launch_bounds__(512, 2) void k_gemm01(
    const bf16* __restrict__ xbf, const bf16* __restrict__ Wt,
    const float* __restrict__ bias, bf16* __restrict__ Gout,
    bf16* __restrict__ xl0, const float* __restrict__ ssq_x,
    float* __restrict__ ssq_out) {
  const int lin = blockIdx.x;
  const int sw = (lin & 7) * 96 + (lin >> 3);
  int bx, by;
  bool isG;
  if (sw < 256) {
    isG = true; bx = sw & 15; by = sw >> 4;
    if (bx < by) return;  // G symmetric: upper triangle only
  } else {
    isG = false; int r = sw - 256; bx = r & 15; by = r >> 4;
  }
  __shared__ char smem[131072];

  float gate = 0.f;
  if (!isG) gate = (*ssq_x > 1.0f) ? 0.f : -1.f;
  VMW(0);  // drain gate load so manual vmcnt counts stay exact

  f32x4 acc[8][4];
  run_core(isG ? Wt : xbf, Wt, 4096, bx, by, smem, acc);

  const int t = threadIdx.x;
  const int w = t >> 6, lane = t & 63;
  const int q = lane >> 4, lr = lane & 15;
  const int wm = w & 1, wn = w >> 1;
  const int N = 4096;
  float ssql = 0.f;
#pragma unroll
  for (int mi = 0; mi < 8; ++mi) {
    const int grow = by * 256 + ((mi & 4) ? 128 : 0) + wm * 64 + (mi & 3) * 16 + q * 4;
#pragma unroll
    for (int r = 0; r < 4; ++r) {
      const size_t rowb = (size_t)(grow + r) * N;
#pragma unroll
      for (int ni = 0; ni < 4; ++ni) {
        const int gcol = bx * 256 + ((ni & 2) ? 128 : 0) + wn * 32 + (ni & 1) * 16 + lr;
        const size_t idx = rowb + gcol;
        float v = acc[mi][ni][r];
        if (isG) {
          Gout[idx] = (bf16)v;
          if (bx != by) Gout[(size_t)gcol * N + (grow + r)] = (bf16)v;
        } else {
          float xl = v + bias[gcol] + gate;
          xl0[idx] = (bf16)xl;
          ssql += xl * xl;
        }
      }
    }
  }
  if (!isG) {
#pragma unroll
    for (int off = 32; off; off >>= 1) ssql += __shfl_down(ssql, off);
    __syncthreads();  // pipeline drained; reuse smem for reduction
    float* red = (float*)smem;
    if (lane == 0) red[w] = ssql;
    __syncthreads();
    if (t == 0) {
      float s = 0.f;
#pragma unroll
      for (int i = 0; i < 8; ++i) s += red[i];
      atomicAdd(ssq_out, s);
    }
  }
}

// ---------------------------------------------------------------- MODE2/3 kernels
// MODE 2: xl1 = 2*xl0 - A@G + (gate1-gate0) ; bf_out ; ssq_out   [A = xl0]
// MODE 3: out = xl_prev - A@G + xl0 + (gate2-gate0)  (fp32)      [A = xl1]
template <int MODE>
__global__ __launch_bounds__(512, 2) void k_gemm23(
    const bf16* __restrict__ A, const bf16* __restrict__ Gt,
    const bf16* __restrict__ xl0, const bf16* __restrict__ xl_prev,
    float* __restrict__ f32_out, bf16* __restrict__ bf_out,
    const float* __restrict__ ssq_a, const float* __restrict__ ssq_b,
    float* __restrict__ ssq_out) {
  const int nb = gridDim.x * gridDim.y;  // 512 (%8==0)
  const int lin = blockIdx.y * gridDim.x + blockIdx.x;
  const int sw = (lin & 7) * (nb >> 3) + (lin >> 3);
  const int bx = sw % gridDim.x, by = sw / gridDim.x;
  __shared__ char smem[131072];

  const float g0 = (*ssq_a > 1.0f) ? 0.f : -1.f;
  const float gt = (*ssq_b > 1.0f) ? 0.f : -1.f;
  const float gate = gt - g0;
  VMW(0);

  f32x4 acc[8][4];
  run_core(A, Gt, 4096, bx, by, smem, acc);

  const int t = threadIdx.x;
  const int w = t >> 6, lane = t & 63;
  const int q = lane >> 4, lr = lane & 15;
  const int wm = w & 1, wn = w >> 1;
  const int N = 4096;
  float ssql = 0.f;
#pragma unroll
  for (int mi = 0; mi < 8; ++mi) {
    const int grow = by * 256 + ((mi & 4) ? 128 : 0) + wm * 64 + (mi & 3) * 16 + q * 4;
#pragma unroll
    for (int r = 0; r < 4; ++r) {
      const size_t rowb = (size_t)(grow + r) * N;
#pragma unroll
      for (int ni = 0; ni < 4; ++ni) {
        const int gcol = bx * 256 + ((ni & 2) ? 128 : 0) + wn * 32 + (ni & 1) * 16 + lr;
        const size_t idx = rowb + gcol;
        float v = acc[mi][ni][r];
        if constexpr (MODE == 2) {
          float xl = 2.0f * (float)xl0[idx] - v + gate;
          bf_out[idx] = (bf16)xl;
          ssql += xl * xl;
        } else {
          f32_out[idx] = (float)xl_prev[idx] - v + (float)xl0[idx] + gate;
        }
      }
    }
  }
  if constexpr (MODE == 2) {
#pragma unroll
    for (int off = 32; off; off >>= 1) ssql += __shfl_down(ssql, off);
    __syncthreads();
    float* red = (float*)smem;
    if (lane == 0) red[w] = ssql;
    __syncthreads();
    if (t == 0) {
      float s = 0.f;
#pragma unroll
      for (int i = 0; i < 8; ++i) s += red[i];
      atomicAdd(ssq_out, s);
    }
  }
}

// ----------------------------------------------------------------
extern "C" void kernel_launch(void* const* d_in, const int* in_sizes, int n_in,
                              void* d_out, int out_size, void* d_ws, size_t ws_size,
                              hipStream_t stream) {
  const float* x = (const float*)d_in[0];
  const float* c0 = (const float*)d_in[1];
  const float* c1 = (const float*)d_in[2];
  const float* c2 = (const float*)d_in[3];
  const float* bias = (const float*)d_in[4];
  float* out = (float*)d_out;

  const int B = 8192, F = 4096;
  char* ws = (char*)d_ws;
  float* scal = (float*)ws;                              // [0]=ssq_x [1]=ssq_xl0 [2]=ssq_xl1
  bf16* xbf = (bf16*)(ws + 256);                         // 64 MiB (x bf16; reused as xl1)
  bf16* Wt = (bf16*)(ws + 256 + (size_t)67108864);       // 32 MiB
  bf16* G = (bf16*)(ws + 256 + (size_t)100663296);       // 32 MiB
  bf16* xl0 = (bf16*)(ws + 256 + (size_t)134217728);     // 64 MiB
  bf16* xl1 = xbf;  // xbf dead after mv GEMM

  k_init<<<1, 64, 0, stream>>>(scal);
  k_cast_ssq<<<1024, 256, 0, stream>>>(x, xbf, &scal[0], B * F / 4);
  k_buildW<<<4096, 256, 0, stream>>>(c0, c1, c2, Wt);

  // fused: G = W^T W (triangle+mirror)  ||  xl0 = x@W + bias + gate0
  k_gemm01<<<768, 512, 0, stream>>>(xbf, Wt, bias, G, xl0, &scal[0], &scal[1]);
  dim3 g1(F / 256, B / 256);
  // xl1 = 2*xl0 - xl0@G + (gate1-gate0)
  k_gemm23<2><<<g1, 512, 0, stream>>>(xl0, G, xl0, nullptr, nullptr, xl1,
                                      &scal[0], &scal[1], &scal[2]);
  // out = xl1 - xl1@G + xl0 + (gate2-gate0)
  k_gemm23<3><<<g1, 512, 0, stream>>>(xl1, G, xl0, xl1, out, nullptr,
                                      &scal[0], &scal[2], nullptr);
}

// Round 3
// 983.001 us; speedup vs baseline: 1.4115x; 1.0734x over previous
//
#include <hip/hip_runtime.h>
#include <stdint.h>

typedef __bf16 bf16;
typedef __bf16 bf16x4 __attribute__((ext_vector_type(4)));
typedef __bf16 bf16x8 __attribute__((ext_vector_type(8)));
typedef float f32x4 __attribute__((ext_vector_type(4)));

#define GLD_LDS16(g, l)                                                        \
  __builtin_amdgcn_global_load_lds(                                            \
      (const __attribute__((address_space(1))) void*)(g),                      \
      (__attribute__((address_space(3))) void*)(l), 16, 0, 0)

#define BAR() asm volatile("s_barrier" ::: "memory")
#define VMW(n) asm volatile("s_waitcnt vmcnt(" #n ")" ::: "memory")
#define PRIO(x) __builtin_amdgcn_s_setprio(x)

// ---------------------------------------------------------------- init: zero ssq accumulators
__global__ void k_init(float* s) {
  if (threadIdx.x < 3) s[threadIdx.x] = 0.0f;
}

// ---------------------------------------------------------------- cast x fp32 -> bf16, fused ||x||^2
__global__ void k_cast_ssq(const float* __restrict__ x, bf16* __restrict__ xb,
                           float* __restrict__ ssq, int n4) {
  int tid = blockIdx.x * blockDim.x + threadIdx.x;
  int stride = gridDim.x * blockDim.x;
  const float4* x4 = (const float4*)x;
  bf16x4* xb4 = (bf16x4*)xb;
  float acc = 0.f;
  for (int i = tid; i < n4; i += stride) {
    float4 v = x4[i];
    acc += v.x * v.x + v.y * v.y + v.z * v.z + v.w * v.w;
    bf16x4 b;
    b.x = (bf16)v.x; b.y = (bf16)v.y; b.z = (bf16)v.z; b.w = (bf16)v.w;
    xb4[i] = b;
  }
#pragma unroll
  for (int off = 32; off; off >>= 1) acc += __shfl_down(acc, off);
  __shared__ float red[4];
  if ((threadIdx.x & 63) == 0) red[threadIdx.x >> 6] = acc;
  __syncthreads();
  if (threadIdx.x == 0) atomicAdd(ssq, red[0] + red[1] + red[2] + red[3]);
}

// ---------------------------------------------------------------- build Wt (bf16, [out=4096][in=4096] row-major)
__global__ void k_buildW(const float* __restrict__ c0, const float* __restrict__ c1,
                         const float* __restrict__ c2, bf16* __restrict__ Wt) {
  int t = blockIdx.x * 256 + threadIdx.x;  // 4096 * 16 * 16 threads
  int j = t >> 8;
  int i0 = (t >> 4) & 15;
  int i1 = t & 15;
  int j0 = j >> 8, j1 = (j >> 4) & 15, j2 = j & 15;
  float t0[8];
#pragma unroll
  for (int r1 = 0; r1 < 8; ++r1) t0[r1] = c0[(i0 * 16 + j0) * 8 + r1];
  float a[8];
#pragma unroll
  for (int r2 = 0; r2 < 8; ++r2) {
    float s = 0.f;
#pragma unroll
    for (int r1 = 0; r1 < 8; ++r1) s += t0[r1] * c1[((r1 * 16 + i1) * 16 + j1) * 8 + r2];
    a[r2] = s;
  }
  union { bf16 h[16]; bf16x8 v[2]; } u;
#pragma unroll
  for (int i2 = 0; i2 < 16; ++i2) {
    float s = 0.f;
#pragma unroll
    for (int r2 = 0; r2 < 8; ++r2) s += a[r2] * c2[(r2 * 16 + i2) * 16 + j2];
    u.h[i2] = (bf16)s;
  }
  bf16* dst = Wt + (size_t)j * 4096 + i0 * 256 + i1 * 16;
  ((bf16x8*)dst)[0] = u.v[0];
  ((bf16x8*)dst)[1] = u.v[1];
}

// ---------------------------------------------------------------- Gram cores of G = W^T W (TT ranks 64)
// g0[(j0,j0')][p1=(r1,r1')] = sum_i0 c0[i0,j0,r1] c0[i0,j0',r1']         [256][64]
// g1[p1][j1][j1'][p2=(r2,r2')] = sum_i1 c1[r1,i1,j1,r2] c1[r1',i1,j1',r2'] [64][16][16][64]
// g2[p2][(j2,j2')] = sum_i2 c2[r2,i2,j2] c2[r2',i2,j2']                  [64][256]
__global__ __launch_bounds__(256) void k_gcores(const float* __restrict__ c0,
                                                const float* __restrict__ c1,
                                                const float* __restrict__ c2,
                                                float* __restrict__ g0,
                                                float* __restrict__ g1,
                                                float* __restrict__ g2) {
  int tid = blockIdx.x * 256 + threadIdx.x;
  if (tid < 16384) {  // g0
    int jj = tid >> 6, p1 = tid & 63;
    int j0 = jj >> 4, j0p = jj & 15, r1 = p1 >> 3, r1p = p1 & 7;
    float s = 0.f;
#pragma unroll
    for (int i0 = 0; i0 < 16; ++i0)
      s += c0[(i0 * 16 + j0) * 8 + r1] * c0[(i0 * 16 + j0p) * 8 + r1p];
    g0[tid] = s;
  } else if (tid < 32768) {  // g2
    int k = tid - 16384;
    int p2 = k >> 8, jj = k & 255;
    int r2 = p2 >> 3, r2p = p2 & 7, j2 = jj >> 4, j2p = jj & 15;
    float s = 0.f;
#pragma unroll
    for (int i2 = 0; i2 < 16; ++i2)
      s += c2[(r2 * 16 + i2) * 16 + j2] * c2[(r2p * 16 + i2) * 16 + j2p];
    g2[k] = s;
  } else {  // g1
    int k = tid - 32768;  // k = ((p1*16+j1)*16+j1')*64 + p2
    int p2 = k & 63, rest = k >> 6;
    int j1p = rest & 15, j1 = (rest >> 4) & 15, p1 = rest >> 8;
    int r1 = p1 >> 3, r1p = p1 & 7, r2 = p2 >> 3, r2p = p2 & 7;
    float s = 0.f;
#pragma unroll
    for (int i1 = 0; i1 < 16; ++i1)
      s += c1[((r1 * 16 + i1) * 16 + j1) * 8 + r2] *
           c1[((r1p * 16 + i1) * 16 + j1p) * 8 + r2p];
    g1[k] = s;
  }
}

// ---------------------------------------------------------------- dense G from Gram cores
// block = (j1,j1') [256 blocks]; thread = (j0,j0') [256 thr]; each thread -> 16x16 (j2,j2') patch.
// G[j0*256+j1*16+j2][j0'*256+j1'*16+j2'] = sum_{p1,p2} g0[(j0,j0'),p1] g1[p1,(j1,j1'),p2] g2[p2,(j2,j2')]
__global__ __launch_bounds__(256) void k_buildG(const float* __restrict__ g0,
                                                const float* __restrict__ g1,
                                                const float* __restrict__ g2,
                                                bf16* __restrict__ G) {
  __shared__ float s_g2[16384];   // [p2][jj2]  64 KB
  __shared__ float s_g1[4096];    // [p1][p2]   16 KB (this block's (j1,j1') slice)
  __shared__ float s_g0t[16384];  // [p1][t]    64 KB (transposed: conflict-free read)
  const int t = threadIdx.x;
  const int j1 = blockIdx.x >> 4, j1p = blockIdx.x & 15;
  const int jj1 = j1 * 16 + j1p;

  const float4* g2f4 = (const float4*)g2;
  float4* sg2f4 = (float4*)s_g2;
  for (int k = t; k < 4096; k += 256) sg2f4[k] = g2f4[k];
  const float4* g1f4 = (const float4*)g1;
  float4* sg1f4 = (float4*)s_g1;
  for (int k = t; k < 1024; k += 256) {
    int p1 = k >> 4, q = k & 15;
    sg1f4[k] = g1f4[(p1 * 256 + jj1) * 16 + q];
  }
#pragma unroll
  for (int q = 0; q < 16; ++q) {
    float4 v = ((const float4*)g0)[t * 16 + q];
    s_g0t[(q * 4 + 0) * 256 + t] = v.x;
    s_g0t[(q * 4 + 1) * 256 + t] = v.y;
    s_g0t[(q * 4 + 2) * 256 + t] = v.z;
    s_g0t[(q * 4 + 3) * 256 + t] = v.w;
  }
  __syncthreads();

  // stage 1: m[p2] = sum_p1 g0[(j0,j0'),p1] * g1[p1][p2]
  float m[64];
#pragma unroll
  for (int i = 0; i < 64; ++i) m[i] = 0.f;
#pragma unroll 4
  for (int p1 = 0; p1 < 64; ++p1) {
    float av = s_g0t[p1 * 256 + t];
#pragma unroll
    for (int q = 0; q < 16; ++q) {
      float4 v = ((const float4*)s_g1)[p1 * 16 + q];
      m[q * 4 + 0] += av * v.x; m[q * 4 + 1] += av * v.y;
      m[q * 4 + 2] += av * v.z; m[q * 4 + 3] += av * v.w;
    }
  }

  // stage 2: out[(j2,j2')] = sum_p2 m[p2] * g2[p2][(j2,j2')]
  const int j0 = t >> 4, j0p = t & 15;
  bf16* gb = G + (size_t)(j0 * 256 + j1 * 16) * 4096 + (j0p * 256 + j1p * 16);
  for (int j2 = 0; j2 < 16; ++j2) {
    float o[16];
#pragma unroll
    for (int i = 0; i < 16; ++i) o[i] = 0.f;
#pragma unroll
    for (int p2 = 0; p2 < 64; ++p2) {
      const float4* r = (const float4*)s_g2 + p2 * 64 + j2 * 4;
#pragma unroll
      for (int q = 0; q < 4; ++q) {
        float4 v = r[q];
        o[q * 4 + 0] += m[p2] * v.x; o[q * 4 + 1] += m[p2] * v.y;
        o[q * 4 + 2] += m[p2] * v.z; o[q * 4 + 3] += m[p2] * v.w;
      }
    }
    union { bf16 h[16]; bf16x8 v[2]; } u;
#pragma unroll
    for (int i = 0; i < 16; ++i) u.h[i] = (bf16)o[i];
    bf16* d = gb + (size_t)j2 * 4096;
    ((bf16x8*)d)[0] = u.v[0];
    ((bf16x8*)d)[1] = u.v[1];
  }
}

// ---------------------------------------------------------------- 256x256 8-phase BT-form GEMM core
// C[m,n] = sum_k A[m,k] * Bt[n,k].  BM=BN=256, BK=64, 512 thr = 8 waves (2M x 4N).
// Balanced read schedule {8,4,8,4}/phase via B0 read-ahead:
//   P1: stage A1(T+1)b1 ; LDA0(b0) ; Q00(af,bfr0A)            ; BAR
//   P2: stage A0(T+2)b0 ; LDB1(b0) ; Q01(af,bfr1)             ; BAR
//   P3: stage B0(T+2)b0 ; LDA1(b0) ; Q11(af,bfr1)  ; VMW(4)   ; BAR   <- publish tile T+1
//   P4: stage B1(T+2)b0 ; LDB0(b1)->bfr0B ; Q10(af,bfr0A)     ; BAR
//   P5-P8: mirror for tile T+1 (buf1), publish T+2 at P7, read B0(b0)->bfr0A at P8.
// vmcnt(4) leaves the 2 newest stage-units in flight; youngest drained has 2-phase lead.
// LDS chunk swizzle: slot (row,c) holds global chunk c ^ (row&7) (pre-swizzled source).
#define STAGE_A(h, kt, b)                                                              \
  do {                                                                                 \
    GLD_LDS16(srcA + (size_t)((h) * 128) * K + (kt) * 64,                              \
              smem + (b) * 65536 + (h) * 16384 + wofs);                                \
    GLD_LDS16(srcA + (size_t)((h) * 128 + 64) * K + (kt) * 64,                         \
              smem + (b) * 65536 + (h) * 16384 + 8192 + wofs);                         \
  } while (0)
#define STAGE_B(h, kt, b)                                                              \
  do {                                                                                 \
    GLD_LDS16(srcB + (size_t)((h) * 128) * K + (kt) * 64,                              \
              smem + (b) * 65536 + 32768 + (h) * 16384 + wofs);                        \
    GLD_LDS16(srcB + (size_t)((h) * 128 + 64) * K + (kt) * 64,                         \
              smem + (b) * 65536 + 32768 + (h) * 16384 + 8192 + wofs);                 \
  } while (0)
#define LDA(ms, b)                                                                     \
  do {                                                                                 \
    const char* s_ = smem + (b) * 65536 + (ms) * 16384 + aRow;                         \
    _Pragma("unroll") for (int mi_ = 0; mi_ < 4; ++mi_) {                              \
      af[mi_][0] = *(const bf16x8*)(s_ + mi_ * 2048 + cb0);                            \
      af[mi_][1] = *(const bf16x8*)(s_ + mi_ * 2048 + cb1);                            \
    }                                                                                  \
  } while (0)
#define LDBX(ns, b, DST)                                                               \
  do {                                                                                 \
    const char* s_ = smem + (b) * 65536 + 32768 + (ns) * 16384 + bRow;                 \
    _Pragma("unroll") for (int ni_ = 0; ni_ < 2; ++ni_) {                              \
      DST[ni_][0] = *(const bf16x8*)(s_ + ni_ * 2048 + cb0);                           \
      DST[ni_][1] = *(const bf16x8*)(s_ + ni_ * 2048 + cb1);                           \
    }                                                                                  \
  } while (0)
#define MQ(ms, ns, BSRC)                                                               \
  do {                                                                                 \
    PRIO(1);                                                                           \
    _Pragma("unroll") for (int mi_ = 0; mi_ < 4; ++mi_)                                \
    _Pragma("unroll") for (int ni_ = 0; ni_ < 2; ++ni_)                                \
    _Pragma("unroll") for (int ks_ = 0; ks_ < 2; ++ks_)                                \
        acc[(ms) * 4 + mi_][(ns) * 2 + ni_] =                                          \
            __builtin_amdgcn_mfma_f32_16x16x32_bf16(                                   \
                af[mi_][ks_], BSRC[ni_][ks_],                                          \
                acc[(ms) * 4 + mi_][(ns) * 2 + ni_], 0, 0, 0);                         \
    PRIO(0);                                                                           \
  } while (0)

__device__ __forceinline__ void run_core(const bf16* __restrict__ Ag,
                                         const bf16* __restrict__ Bg, const int K,
                                         const int bx, const int by, char* smem,
                                         f32x4 (&acc)[8][4]) {
  const int t = threadIdx.x;
  const int w = t >> 6, lane = t & 63;
  const int q = lane >> 4, lr = lane & 15;
  const int wm = w & 1, wn = w >> 1;

  const int r0 = t >> 3;
  const int ksrc = (t & 7) ^ (r0 & 7);
  const bf16* srcA = Ag + (size_t)(by * 256 + r0) * K + ksrc * 8;
  const bf16* srcB = Bg + (size_t)(bx * 256 + r0) * K + ksrc * 8;
  const int wofs = w << 10;

  const int aRow = (wm * 64 + lr) * 128;
  const int bRow = (wn * 32 + lr) * 128;
  const int cb0 = ((q ^ (lr & 7)) << 4);
  const int cb1 = (((4 + q) ^ (lr & 7)) << 4);

#pragma unroll
  for (int i = 0; i < 8; ++i)
#pragma unroll
    for (int j = 0; j < 4; ++j) acc[i][j] = (f32x4){0.f, 0.f, 0.f, 0.f};

  bf16x8 af[4][2];        // current m-sub A frags (same-phase read)
  bf16x8 bfr1[2][2];      // B1 frags (same-tile)
  bf16x8 bfr0A[2][2];     // B0 frags for buf0 tiles (read-ahead at P8/pre-loop)
  bf16x8 bfr0B[2][2];     // B0 frags for buf1 tiles (read-ahead at P4)

  // prologue: tile0 (buf0) all 4 units + tile1 (buf1) A0,B0,B1.
  // VMW(6): tile0's 8 loads landed; tile1's 6 stay in flight (= steady-state leftover).
  STAGE_A(0, 0, 0); STAGE_B(0, 0, 0); STAGE_B(1, 0, 0); STAGE_A(1, 0, 0);
  STAGE_A(0, 1, 1); STAGE_B(0, 1, 1); STAGE_B(1, 1, 1);
  VMW(6);
  BAR();
  LDBX(0, 0, bfr0A);      // pre-read B0 of tile0

  const int NT = K >> 6;  // 64 K-tiles
#pragma unroll 1
  for (int tt = 0; tt < (NT >> 1) - 1; ++tt) {
    const int T = tt << 1;
    // ---- tile T (buf0) ----
    STAGE_A(1, T + 1, 1);   // buf1.A1: last read P7 prev iter
    LDA(0, 0);
    MQ(0, 0, bfr0A);
    BAR();
    STAGE_A(0, T + 2, 0);   // buf0.A0: read P1
    LDBX(1, 0, bfr1);
    MQ(0, 1, bfr1);
    BAR();
    STAGE_B(0, T + 2, 0);   // buf0.B0: read P8 prev iter (retired P1)
    LDA(1, 0);
    MQ(1, 1, bfr1);
    VMW(4);                 // publish tile T+1 (buf1 complete)
    BAR();
    STAGE_B(1, T + 2, 0);   // buf0.B1: read P2
    LDBX(0, 1, bfr0B);      // read-ahead: B0 of tile T+1 (published at P3)
    MQ(1, 0, bfr0A);
    BAR();
    // ---- tile T+1 (buf1) ----
    STAGE_A(1, T + 2, 0);   // buf0.A1: read P3
    LDA(0, 1);
    MQ(0, 0, bfr0B);
    BAR();
    STAGE_A(0, T + 3, 1);   // buf1.A0: read P5
    LDBX(1, 1, bfr1);
    MQ(0, 1, bfr1);
    BAR();
    STAGE_B(0, T + 3, 1);   // buf1.B0: read P4 (retired P5)
    LDA(1, 1);
    MQ(1, 1, bfr1);
    VMW(4);                 // publish tile T+2 (buf0 complete)
    BAR();
    STAGE_B(1, T + 3, 1);   // buf1.B1: read P6
    LDBX(0, 0, bfr0A);      // read-ahead: B0 of tile T+2 (published at P7)
    MQ(1, 0, bfr0B);
    BAR();
  }

  // epilogue: tiles NT-2 (buf0), NT-1 (buf1); only A1(NT-1) left to stage
  STAGE_A(1, NT - 1, 1);
  LDA(0, 0);
  MQ(0, 0, bfr0A); BAR();
  LDBX(1, 0, bfr1);
  MQ(0, 1, bfr1); BAR();
  LDA(1, 0);
  MQ(1, 1, bfr1);
  VMW(0);                   // tile NT-1 fully landed
  BAR();
  LDBX(0, 1, bfr0B);
  MQ(1, 0, bfr0A);
  BAR();
  LDA(0, 1);
  MQ(0, 0, bfr0B); BAR();
  LDBX(1, 1, bfr1);
  MQ(0, 1, bfr1); BAR();
  LDA(1, 1);
  MQ(1, 1, bfr1); BAR();
  MQ(1, 0, bfr0B);
}

// ---------------------------------------------------------------- GEMM epilogue kernels
// MODE 0: xl0 = A@Wt^T + bias + gate0 ; bf_out ; ssq_out                 [A = xbf]
// MODE 2: xl1 = 2*xl0 - A@G + (gate1-gate0) ; bf_out ; ssq_out          [A = xl0]
// MODE 3: out = xl_prev - A@G + xl0 + (gate2-gate0)  (fp32)             [A = xl1]
template <int MODE>
__global__ __launch_bounds__(512, 2) void k_gemm(
    const bf16* __restrict__ A, const bf16* __restrict__ Bt, int M, int N, int K,
    const float* __restrict__ bias, const bf16* __restrict__ xl0,
    const bf16* __restrict__ xl_prev, float* f32_out, bf16* __restrict__ bf_out,
    const float* __restrict__ ssq_a, const float* __restrict__ ssq_b,
    float* __restrict__ ssq_out) {
  const int nb = gridDim.x * gridDim.y;  // %8==0
  const int lin = blockIdx.y * gridDim.x + blockIdx.x;
  const int sw = (lin & 7) * (nb >> 3) + (lin >> 3);
  const int bx = sw % gridDim.x, by = sw / gridDim.x;
  __shared__ char smem[131072];

  float gate = 0.f;
  if constexpr (MODE == 0) {
    gate = (*ssq_a > 1.0f) ? 0.f : -1.f;
  } else {
    float g0v = (*ssq_a > 1.0f) ? 0.f : -1.f;
    float gtv = (*ssq_b > 1.0f) ? 0.f : -1.f;
    gate = gtv - g0v;
  }
  VMW(0);  // drain gate loads so manual vmcnt counts stay exact

  f32x4 acc[8][4];
  run_core(A, Bt, K, bx, by, smem, acc);

  const int t = threadIdx.x;
  const int w = t >> 6, lane = t & 63;
  const int q = lane >> 4, lr = lane & 15;
  const int wm = w & 1, wn = w >> 1;
  float ssql = 0.f;
#pragma unroll
  for (int mi = 0; mi < 8; ++mi) {
    const int grow = by * 256 + ((mi & 4) ? 128 : 0) + wm * 64 + (mi & 3) * 16 + q * 4;
#pragma unroll
    for (int r = 0; r < 4; ++r) {
      const size_t rowb = (size_t)(grow + r) * N;
#pragma unroll
      for (int ni = 0; ni < 4; ++ni) {
        const int gcol = bx * 256 + ((ni & 2) ? 128 : 0) + wn * 32 + (ni & 1) * 16 + lr;
        const size_t idx = rowb + gcol;
        float v = acc[mi][ni][r];
        if constexpr (MODE == 0) {
          float xl = v + bias[gcol] + gate;
          bf_out[idx] = (bf16)xl;
          ssql += xl * xl;
        } else if constexpr (MODE == 2) {
          float xl = 2.0f * (float)xl0[idx] - v + gate;
          bf_out[idx] = (bf16)xl;
          ssql += xl * xl;
        } else {
          f32_out[idx] = (float)xl_prev[idx] - v + (float)xl0[idx] + gate;
        }
      }
    }
  }
  if constexpr (MODE == 0 || MODE == 2) {
#pragma unroll
    for (int off = 32; off; off >>= 1) ssql += __shfl_down(ssql, off);
    __syncthreads();  // pipeline drained; reuse smem for reduction
    float* red = (float*)smem;
    if (lane == 0) red[w] = ssql;
    __syncthreads();
    if (t == 0) {
      float s = 0.f;
#pragma unroll
      for (int i = 0; i < 8; ++i) s += red[i];
      atomicAdd(ssq_out, s);
    }
  }
}

// ----------------------------------------------------------------
extern "C" void kernel_launch(void* const* d_in, const int* in_sizes, int n_in,
                              void* d_out, int out_size, void* d_ws, size_t ws_size,
                              hipStream_t stream) {
  const float* x = (const float*)d_in[0];
  const float* c0 = (const float*)d_in[1];
  const float* c1 = (const float*)d_in[2];
  const float* c2 = (const float*)d_in[3];
  const float* bias = (const float*)d_in[4];
  float* out = (float*)d_out;

  const int B = 8192, F = 4096;
  char* ws = (char*)d_ws;
  float* scal = (float*)ws;                              // [0]=ssq_x [1]=ssq_xl0 [2]=ssq_xl1
  bf16* xbf = (bf16*)(ws + 256);                         // 64 MiB (x bf16; reused as xl1)
  bf16* Wt = (bf16*)(ws + 256 + (size_t)67108864);       // 32 MiB
  bf16* G = (bf16*)(ws + 256 + (size_t)100663296);       // 32 MiB
  bf16* xl0 = (bf16*)(ws + 256 + (size_t)134217728);     // 64 MiB
  bf16* xl1 = xbf;  // xbf dead after mv GEMM
  // Gram-core scratch lives in the (not-yet-written) xl0 region: 4.25 MiB << 64 MiB.
  float* g0 = (float*)xl0;           // 64 KB
  float* g2 = g0 + 16384;            // 64 KB
  float* g1 = g2 + 16384;            // 4 MiB

  k_init<<<1, 64, 0, stream>>>(scal);
  k_cast_ssq<<<1024, 256, 0, stream>>>(x, xbf, &scal[0], B * F / 4);
  k_buildW<<<4096, 256, 0, stream>>>(c0, c1, c2, Wt);

  // G = W^T W built directly from TT cores (no 4096^3 GEMM round)
  k_gcores<<<4224, 256, 0, stream>>>(c0, c1, c2, g0, g1, g2);
  k_buildG<<<256, 256, 0, stream>>>(g0, g1, g2, G);

  dim3 g1d(F / 256, B / 256);
  // xl0 = x@W + bias + gate0
  k_gemm<0><<<g1d, 512, 0, stream>>>(xbf, Wt, B, F, F, bias, nullptr, nullptr,
                                     nullptr, xl0, &scal[0], nullptr, &scal[1]);
  // xl1 = 2*xl0 - xl0@G + (gate1-gate0)
  k_gemm<2><<<g1d, 512, 0, stream>>>(xl0, G, B, F, F, nullptr, xl0, nullptr,
                                     nullptr, xl1, &scal[0], &scal[1], &scal[2]);
  // out = xl1 - xl1@G + xl0 + (gate2-gate0)
  k_gemm<3><<<g1d, 512, 0, stream>>>(xl1, G, B, F, F, nullptr, xl0, xl1,
                                     out, nullptr, &scal[0], &scal[2], nullptr);
}